// Round 4
// baseline (124.856 us; speedup 1.0000x reference)
//
#include <hip/hip_runtime.h>

#define TT 8192
#define DD 64
#define MODS 4
#define NCH 256
#define CH  32    // TT / NCH

typedef __attribute__((ext_vector_type(8))) short bf16x8;
typedef __attribute__((ext_vector_type(4))) float f32x4;

// round-to-nearest-even fp32 -> bf16 bits
__device__ __forceinline__ unsigned f2bf1(float x) {
    unsigned u = __float_as_uint(x);
    return (u + 0x7FFFu + ((u >> 16) & 1u)) >> 16;
}
__device__ __forceinline__ unsigned packbf(float a, float b) {
    return f2bf1(a) | (f2bf1(b) << 16);
}

// ---------------------------------------------------------------------------
// Kernel 1: the 5 MLPs via bf16 MFMA, computing y^T = W^T x^T per layer.
// grid = (TT/64, 5 jobs), block 256 = 4 waves; each wave owns 16 rows.
//   A-frag = W[d][c] loaded DIRECTLY from fp32 global (strided dword, 4
//            cache lines/instr, L1-hot) + in-register bf16 pack — no wt_prep.
//   B-frag = x rows from LDS (pitch 72 bf16, bank-balanced b128)
//   C lane layout (m89-verified): col(lane&15)=row r, rowC(quad*4+reg)=col c
// Waves touch only their own 16 LDS rows: NO barriers at all.
// ---------------------------------------------------------------------------
__global__ __launch_bounds__(256)
void mlp_kernel(const float* __restrict__ X,
                const float* __restrict__ wq_w, const float* __restrict__ wq_b,
                const float* __restrict__ wk_w, const float* __restrict__ wk_b,
                float* __restrict__ Q, float* __restrict__ Kout)
{
    __shared__ unsigned short xbuf[4][16][72];   // 9,216 B

    const int job = blockIdx.y;
    const float *xin, *Wj, *Bias;
    float* out;
    if (job == 0) { xin = X; Wj = wq_w; Bias = wq_b; out = Q; }
    else {
        const int m = job - 1;
        xin  = X    + (size_t)m * TT * DD;
        Wj   = wk_w + (size_t)m * 3 * DD * DD;
        Bias = wk_b + (size_t)m * 3 * DD;
        out  = Kout + (size_t)m * TT * DD;
    }

    const int wv   = threadIdx.x >> 6;
    const int lane = threadIdx.x & 63;
    const int quad = lane >> 4;
    const int l15  = lane & 15;
    const int row0 = blockIdx.x * 64 + wv * 16;   // this wave's 16 rows
    unsigned short* xb = &xbuf[wv][0][0];         // [16][72]

    // ---- stage this wave's 16x64 fp32 rows as bf16 into LDS ----
    {
        const float4* src = (const float4*)(xin + (size_t)row0 * DD);
        #pragma unroll
        for (int k = 0; k < 4; ++k) {
            int f = lane + 64 * k;                // float4 idx 0..255
            int r = f >> 4, c4 = (f & 15) << 2;   // row, col
            float4 v = src[f];
            uint2 p = make_uint2(packbf(v.x, v.y), packbf(v.z, v.w));
            *(uint2*)&xb[r * 72 + c4] = p;        // 8B aligned
        }
    }

    #pragma unroll
    for (int l = 0; l < 3; ++l) {
        const float* Wl = Wj + (size_t)l * DD * DD;   // fp32 [d][c]
        const float* Bl = Bias + l * DD;

        f32x4 acc[4];
        #pragma unroll
        for (int mt = 0; mt < 4; ++mt) {          // acc init = bias (C operand)
            float4 b4 = *(const float4*)(Bl + 16 * mt + quad * 4);
            acc[mt][0] = b4.x; acc[mt][1] = b4.y; acc[mt][2] = b4.z; acc[mt][3] = b4.w;
        }

        bf16x8 xf[2];                             // B-frags: x[r=l15][k=quad*8+j+32kt]
        #pragma unroll
        for (int kt = 0; kt < 2; ++kt)
            xf[kt] = *(const bf16x8*)&xb[l15 * 72 + quad * 8 + kt * 32];

        #pragma unroll
        for (int mt = 0; mt < 4; ++mt) {
            #pragma unroll
            for (int kt = 0; kt < 2; ++kt) {
                // A-frag: A[c = 16mt+l15][d = quad*8+32kt+j] = W[d][c], j=0..7
                const float* wp = Wl + (size_t)(quad * 8 + 32 * kt) * DD + 16 * mt + l15;
                float w0 = wp[0 * DD], w1 = wp[1 * DD], w2 = wp[2 * DD], w3 = wp[3 * DD];
                float w4 = wp[4 * DD], w5 = wp[5 * DD], w6 = wp[6 * DD], w7 = wp[7 * DD];
                union { bf16x8 v; unsigned u[4]; } wf;
                wf.u[0] = packbf(w0, w1); wf.u[1] = packbf(w2, w3);
                wf.u[2] = packbf(w4, w5); wf.u[3] = packbf(w6, w7);
                acc[mt] = __builtin_amdgcn_mfma_f32_16x16x32_bf16(wf.v, xf[kt], acc[mt], 0, 0, 0);
            }
        }

        if (l < 2) {                              // relu + pack + writeback
            #pragma unroll
            for (int mt = 0; mt < 4; ++mt) {
                float r0 = fmaxf(acc[mt][0], 0.f), r1 = fmaxf(acc[mt][1], 0.f);
                float r2 = fmaxf(acc[mt][2], 0.f), r3 = fmaxf(acc[mt][3], 0.f);
                uint2 p = make_uint2(packbf(r0, r1), packbf(r2, r3));
                // cols c = 16mt + quad*4 .. +3 of row r=l15
                *(uint2*)&xb[l15 * 72 + 16 * mt + quad * 4] = p;
            }
        } else {                                  // final: store fp32
            #pragma unroll
            for (int mt = 0; mt < 4; ++mt) {
                float4 v = make_float4(acc[mt][0], acc[mt][1], acc[mt][2], acc[mt][3]);
                *(float4*)(out + (size_t)(row0 + l15) * DD + 16 * mt + quad * 4) = v;
            }
        }
    }
}

// ---------------------------------------------------------------------------
// Kernel 2: per-chunk partial sums of K[t,d]*V[t,e], CH=32 rows/chunk.
// grid = (NCH, MODS) = 1024 blocks, block 128 (thread = e*64+d). Coalesced.
// ---------------------------------------------------------------------------
__global__ __launch_bounds__(128)
void scan_partial(const float* __restrict__ Kin, const float* __restrict__ X,
                  float* __restrict__ Ctot)
{
    const int m = blockIdx.y, ch = blockIdx.x;
    const int tid = threadIdx.x;
    const int d = tid & 63, e = tid >> 6;
    const float* Kb = Kin + ((size_t)m * TT + (size_t)ch * CH) * DD;
    const float* Vb = X   + ((size_t)m * TT + (size_t)ch * CH) * DD;
    float acc = 0.f;
    #pragma unroll 8
    for (int tt = 0; tt < CH; ++tt)
        acc = fmaf(Kb[tt * DD + d], Vb[tt * DD + e], acc);
    Ctot[((size_t)m * NCH + ch) * 128 + tid] = acc;
}

// ---------------------------------------------------------------------------
// Kernel 3: exclusive prefix over chunks: Pre[m][c] = sum_{c'<c} Ctot[m][c'].
// grid = MODS blocks x 128 threads; serial over 256 chunks (loads batch
// under unroll; only the fp32 add chain is dependent). 1 MB total traffic.
// ---------------------------------------------------------------------------
__global__ __launch_bounds__(128)
void scan_prefix(const float* __restrict__ Ctot, float* __restrict__ Pre)
{
    const int m = blockIdx.x;
    const int tid = threadIdx.x;
    float acc = 0.f;
    #pragma unroll 8
    for (int c = 0; c < NCH; ++c) {
        Pre[((size_t)m * NCH + c) * 128 + tid] = acc;
        acc += Ctot[((size_t)m * NCH + c) * 128 + tid];
    }
}

// ---------------------------------------------------------------------------
// Kernel 4: per-query gather. One wave per query; 4 interleaved binary
// searches (wave-uniform addresses); chunk base from Pre (512B coalesced);
// <=32-row recompute from L1/L2-hot K; butterfly reduce.
// ---------------------------------------------------------------------------
__global__ __launch_bounds__(256)
void gather_kernel(const float* __restrict__ X, const float* __restrict__ Q,
                   const float* __restrict__ Kin, const float* __restrict__ Pre,
                   float* __restrict__ out)
{
    const int q    = (blockIdx.x << 2) + (threadIdx.x >> 6);
    const int lane = threadIdx.x & 63;
    const float t1 = X[(size_t)q * DD + 63];
    const float qv = Q[(size_t)q * DD + lane];

    const float* X1 = X + (size_t)TT * DD;
    const float* X2 = X + (size_t)2 * TT * DD;
    const float* X3 = X + (size_t)3 * TT * DD;

    int lo0 = 0, hi0 = TT, lo1 = 0, hi1 = TT;
    int lo2 = 0, hi2 = TT, lo3 = 0, hi3 = TT;
    #pragma unroll 1
    for (int s = 0; s < 13; ++s) {    // 2^13 == TT, exactly 13 steps
        int md0 = (lo0 + hi0) >> 1, md1 = (lo1 + hi1) >> 1;
        int md2 = (lo2 + hi2) >> 1, md3 = (lo3 + hi3) >> 1;
        float v0 = X [(size_t)md0 * DD + 63];
        float v1 = X1[(size_t)md1 * DD + 63];
        float v2 = X2[(size_t)md2 * DD + 63];
        float v3 = X3[(size_t)md3 * DD + 63];
        if (v0 <= t1) lo0 = md0 + 1; else hi0 = md0;
        if (v1 <= t1) lo1 = md1 + 1; else hi1 = md1;
        if (v2 <= t1) lo2 = md2 + 1; else hi2 = md2;
        if (v3 <= t1) lo3 = md3 + 1; else hi3 = md3;
    }

    float a0 = 0.f, a1 = 0.f;
    const int idx[4] = { lo0 - 1, lo1 - 1, lo2 - 1, lo3 - 1 };
    #pragma unroll
    for (int m = 0; m < MODS; ++m) {
        const int id = idx[m];
        if (id >= 0) {
            const int c = id >> 5;                 // chunk index (CH=32)
            const float* P  = Pre + ((size_t)m * NCH + c) * 128;
            float s0 = P[lane];                    // S base, e=0
            float s1 = P[64 + lane];               // S base, e=1
            const float* Kb = Kin + ((size_t)m * TT + (size_t)c * CH) * DD;
            const float* Vb = X   + ((size_t)m * TT + (size_t)c * CH) * DD;
            const int n = id - c * CH;             // 0..31, wave-uniform
            #pragma unroll 4
            for (int t = 0; t <= n; ++t) {
                float kv = Kb[t * DD + lane];
                s0 = fmaf(kv, Vb[t * DD],     s0);
                s1 = fmaf(kv, Vb[t * DD + 1], s1);
            }
            a0 = fmaf(qv, s0, a0);
            a1 = fmaf(qv, s1, a1);
        }
    }
    #pragma unroll
    for (int off = 32; off > 0; off >>= 1) {
        a0 += __shfl_xor(a0, off, 64);
        a1 += __shfl_xor(a1, off, 64);
    }
    if (lane == 0) {
        out[(q << 1)]     = a0;
        out[(q << 1) + 1] = a1;
    }
}

extern "C" void kernel_launch(void* const* d_in, const int* in_sizes, int n_in,
                              void* d_out, int out_size, void* d_ws, size_t ws_size,
                              hipStream_t stream)
{
    const float* X    = (const float*)d_in[0];
    const float* wq_w = (const float*)d_in[1];
    const float* wq_b = (const float*)d_in[2];
    const float* wk_w = (const float*)d_in[3];
    const float* wk_b = (const float*)d_in[4];
    float* out = (float*)d_out;

    float* ws   = (float*)d_ws;
    float* Q    = ws;                                   // TT*DD             (2 MB)
    float* K    = Q    + (size_t)TT * DD;               // MODS*TT*DD        (8 MB)
    float* Ctot = K    + (size_t)MODS * TT * DD;        // MODS*NCH*128      (512 KB)
    float* Pre  = Ctot + (size_t)MODS * NCH * 128;      // MODS*NCH*128      (512 KB)

    mlp_kernel   <<<dim3(TT/64, 5),  256, 0, stream>>>(X, wq_w, wq_b, wk_w, wk_b, Q, K);
    scan_partial <<<dim3(NCH, MODS), 128, 0, stream>>>(K, X, Ctot);
    scan_prefix  <<<MODS,            128, 0, stream>>>(Ctot, Pre);
    gather_kernel<<<TT / 4,          256, 0, stream>>>(X, Q, K, Pre, out);
}